// Round 4
// baseline (240.842 us; speedup 1.0000x reference)
//
#include <hip/hip_runtime.h>

#define B_DIM 8
#define N_DIM 2048
#define C_DIM 256
#define K_SEL 1024

// ---------------- LayerNorm, faithful numpy execution ----------------
// mu: reduce over STRIDED axis of the transposed view -> nditer outer-reduction:
//     single sequential ascending-c chain (init = copy of c=0 slice, then 255 adds).
// var: (x-mu) materializes CONTIGUOUS -> reduce over contiguous axis -> numpy
//     pairwise_sum: 256 = 128+128 halves, each with 8 interleaved accumulators
//     r[j] += d2[8i+j], combined ((r0+r1)+(r2+r3))+((r4+r5)+(r6+r7)).
// /256 exact (pow2). r = 1/sqrt(var+1e-6f). f = ((d*r)*gamma)+beta.
__global__ __launch_bounds__(256) void ln_np2(const float* __restrict__ feat,
    const float* __restrict__ gamma, const float* __restrict__ beta,
    float* __restrict__ fbuf) {
  const int m = blockIdx.x * 256 + threadIdx.x;   // row b*2048+n
  const int b = m >> 11, n = m & 2047;
  const float* xb = feat + ((long)b << 19) + n;   // element c at xb[c<<11]

  // --- mean: sequential ascending single chain ---
  float acc = xb[0];
  for (int c = 1; c < 256; ++c) acc = __fadd_rn(acc, xb[(long)c << 11]);
  const float mu = __fdiv_rn(acc, 256.0f);        // /256 exact

  // --- var: numpy pairwise (2 halves x 8 accumulators), d^2 via separate mul ---
  float pw[2];
#pragma unroll
  for (int blk = 0; blk < 2; ++blk) {
    const int c0 = blk << 7;
    float r8[8];
#pragma unroll
    for (int j = 0; j < 8; ++j) {
      float d = __fsub_rn(xb[(long)(c0 + j) << 11], mu);
      r8[j] = __fmul_rn(d, d);
    }
    for (int i = 8; i < 128; i += 8) {
#pragma unroll
      for (int j = 0; j < 8; ++j) {
        float d = __fsub_rn(xb[(long)(c0 + i + j) << 11], mu);
        r8[j] = __fadd_rn(r8[j], __fmul_rn(d, d));
      }
    }
    pw[blk] = __fadd_rn(__fadd_rn(__fadd_rn(r8[0], r8[1]), __fadd_rn(r8[2], r8[3])),
                        __fadd_rn(__fadd_rn(r8[4], r8[5]), __fadd_rn(r8[6], r8[7])));
  }
  const float var = __fdiv_rn(__fadd_rn(pw[0], pw[1]), 256.0f);
  const float rs = __fdiv_rn(1.0f, __fsqrt_rn(__fadd_rn(var, 1e-6f)));

  float* frow = fbuf + ((long)m << 8);
  for (int c = 0; c < 256; ++c) {
    float v = __fmul_rn(__fsub_rn(xb[(long)c << 11], mu), rs);
    v = __fadd_rn(__fmul_rn(v, gamma[c]), beta[c]);   // exact no-ops for ones/zeros
    frow[c] = v;
  }
}

// ---------------- f32 64x64-tile GEMM, single ascending-k FMA chain (OpenBLAS sgemm) ----------------
template <bool RELU, bool GATHER>
__global__ void __launch_bounds__(256) gemm_f32(
    const float* __restrict__ Ap, const float* __restrict__ Bw,
    const float* __restrict__ bias, const int* __restrict__ rowmap,
    float* __restrict__ Cout) {
  __shared__ __align__(16) float As[16][68];
  __shared__ __align__(16) float Bs[16][68];
  const int t = threadIdx.x;
  const int m0 = blockIdx.y << 6, c0 = blockIdx.x << 6;
  const int tx = t & 15, ty = t >> 4;
  const int ar = t >> 2, ak = (t & 3) << 2;
  long arow;
  if (GATHER) {
    int m = m0 + ar;
    arow = ((long)(((m >> 10) << 11) + rowmap[m])) << 8;  // b*2048 + idx
  } else {
    arow = ((long)(m0 + ar)) << 8;
  }
  const int bk = t >> 4, bc = (t & 15) << 2;
  float acc[4][4] = {};
  for (int k0 = 0; k0 < 256; k0 += 16) {
    const float4 av = *(const float4*)(Ap + arow + k0 + ak);
    const float4 bv = *(const float4*)(Bw + (((k0 + bk) << 8) + c0 + bc));
    As[ak + 0][ar] = av.x; As[ak + 1][ar] = av.y;
    As[ak + 2][ar] = av.z; As[ak + 3][ar] = av.w;
    *(float4*)&Bs[bk][bc] = bv;
    __syncthreads();
#pragma unroll
    for (int kk = 0; kk < 16; ++kk) {   // strict ascending k: one FMA chain per (m,c)
      const float4 a = *(const float4*)&As[kk][ty << 2];
      const float4 b = *(const float4*)&Bs[kk][tx << 2];
      acc[0][0]=__fmaf_rn(a.x,b.x,acc[0][0]); acc[0][1]=__fmaf_rn(a.x,b.y,acc[0][1]);
      acc[0][2]=__fmaf_rn(a.x,b.z,acc[0][2]); acc[0][3]=__fmaf_rn(a.x,b.w,acc[0][3]);
      acc[1][0]=__fmaf_rn(a.y,b.x,acc[1][0]); acc[1][1]=__fmaf_rn(a.y,b.y,acc[1][1]);
      acc[1][2]=__fmaf_rn(a.y,b.z,acc[1][2]); acc[1][3]=__fmaf_rn(a.y,b.w,acc[1][3]);
      acc[2][0]=__fmaf_rn(a.z,b.x,acc[2][0]); acc[2][1]=__fmaf_rn(a.z,b.y,acc[2][1]);
      acc[2][2]=__fmaf_rn(a.z,b.z,acc[2][2]); acc[2][3]=__fmaf_rn(a.z,b.w,acc[2][3]);
      acc[3][0]=__fmaf_rn(a.w,b.x,acc[3][0]); acc[3][1]=__fmaf_rn(a.w,b.y,acc[3][1]);
      acc[3][2]=__fmaf_rn(a.w,b.z,acc[3][2]); acc[3][3]=__fmaf_rn(a.w,b.w,acc[3][3]);
    }
    __syncthreads();
  }
  const int cc = c0 + (tx << 2);
#pragma unroll
  for (int r = 0; r < 4; ++r) {
    float o0 = __fadd_rn(acc[r][0], bias[cc + 0]);
    float o1 = __fadd_rn(acc[r][1], bias[cc + 1]);
    float o2 = __fadd_rn(acc[r][2], bias[cc + 2]);
    float o3 = __fadd_rn(acc[r][3], bias[cc + 3]);
    if (RELU) { o0 = fmaxf(o0,0.0f); o1 = fmaxf(o1,0.0f); o2 = fmaxf(o2,0.0f); o3 = fmaxf(o3,0.0f); }
    float4 o; o.x=o0; o.y=o1; o.z=o2; o.w=o3;
    *(float4*)(Cout + (((long)(m0 + (ty << 2) + r)) << 8) + cc) = o;
  }
}

// ---------------- w = h @ Wd2 : sgemm N=1 edge kernel = single ascending FMA chain ----------------
// key = (w + bd2) / 0.1f  (/t rounding = the coarsest quantizer in the ref's softmax ladder)
__global__ __launch_bounds__(256) void wchain(const float* __restrict__ h,
    const float* __restrict__ Wd2, const float* __restrict__ bd2,
    float* __restrict__ wkey) {
  const int m = blockIdx.x * 256 + threadIdx.x;
  const float* hr = h + ((long)m << 8);
  float acc = 0.0f;
  for (int c = 0; c < 256; ++c) acc = __fmaf_rn(hr[c], Wd2[c], acc);
  const float w = __fadd_rn(acc, bd2[0]);
  wkey[m] = __fdiv_rn(w, 0.1f);
}

// ---------------- per-batch top-K via bitonic sort (key desc, tie: lower idx) ----------------
__global__ void __launch_bounds__(1024) topk_kernel(
    const float* __restrict__ wv, const float* __restrict__ xyzs,
    int* __restrict__ idx_out, float* __restrict__ out_xyz,
    float* __restrict__ out_idx) {
  __shared__ float vals[2048];
  __shared__ int idxs[2048];
  const int b = blockIdx.x, t = threadIdx.x;
  vals[t] = wv[(b << 11) + t]; idxs[t] = t;
  vals[t + 1024] = wv[(b << 11) + t + 1024]; idxs[t + 1024] = t + 1024;
  __syncthreads();
  for (int k = 2; k <= 2048; k <<= 1) {
    for (int j = k >> 1; j > 0; j >>= 1) {
      for (int half = 0; half < 2; ++half) {
        int i = (half << 10) | t;
        int ixj = i ^ j;
        if (ixj > i) {
          float vi = vals[i], vj = vals[ixj];
          int ii = idxs[i], ij = idxs[ixj];
          bool before = (vi > vj) || (vi == vj && ii < ij);
          bool up = ((i & k) == 0);
          if (before != up) {
            vals[i] = vj; vals[ixj] = vi;
            idxs[i] = ij; idxs[ixj] = ii;
          }
        }
      }
      __syncthreads();
    }
  }
  const int sel = idxs[t];     // rank t == selection step t
  idx_out[(b << 10) + t] = sel;
  out_idx[(b << 10) + t] = (float)sel;
  const long o = ((long)((b << 10) + t)) * 3;
  const long s3 = ((long)((b << 11) + sel)) * 3;
  out_xyz[o] = xyzs[s3]; out_xyz[o + 1] = xyzs[s3 + 1]; out_xyz[o + 2] = xyzs[s3 + 2];
}

// ---------------- feats transpose: nf (B*K, C) -> out (B, C, K) ----------------
__global__ void __launch_bounds__(256) transpose_kernel(
    const float* __restrict__ nf, float* __restrict__ outf) {
  __shared__ float tile[32][33];
  const int kt = blockIdx.x, ct = blockIdx.y, t = threadIdx.x;
  const int k0 = kt << 5, c0 = ct << 5;
  const int col = t & 31, row8 = t >> 5;
#pragma unroll
  for (int p = 0; p < 4; ++p) {
    int kr = (p << 3) + row8;
    tile[kr][col] = nf[((long)(k0 + kr) << 8) + c0 + col];
  }
  __syncthreads();
  const int bb = k0 >> 10;
  const int kk = k0 & 1023;
#pragma unroll
  for (int p = 0; p < 4; ++p) {
    int cr = (p << 3) + row8;
    outf[((long)((bb << 8) + c0 + cr) << 10) + kk + col] = tile[col][cr];
  }
}

extern "C" void kernel_launch(void* const* d_in, const int* in_sizes, int n_in,
                              void* d_out, int out_size, void* d_ws, size_t ws_size,
                              hipStream_t stream) {
  const float* xyzs     = (const float*)d_in[0];
  const float* features = (const float*)d_in[1];
  const float* ln_gamma = (const float*)d_in[2];
  const float* ln_beta  = (const float*)d_in[3];
  const float* Wu1      = (const float*)d_in[4];
  const float* bu1      = (const float*)d_in[5];
  const float* Wu2      = (const float*)d_in[6];
  const float* bu2      = (const float*)d_in[7];
  const float* Wd1      = (const float*)d_in[8];
  const float* bd1      = (const float*)d_in[9];
  const float* Wd2      = (const float*)d_in[10];
  const float* bd2      = (const float*)d_in[11];

  char* ws = (char*)d_ws;
  float* fbuf = (float*)ws;                   // 16384*256 f32
  float* hbuf = (float*)(ws + 16777216);      // 16384*256 f32
  float* hu   = (float*)(ws + 33554432);      //  8192*256 f32
  float* nf   = (float*)(ws + 41943040);      //  8192*256 f32
  float* wv   = (float*)(ws + 50331648);      // 16384 f32
  int*   idx  = (int*)(ws + 50397184);        //  8192 i32

  float* out_xyz  = (float*)d_out;            // (8,1024,3)   = 24576
  float* out_feat = out_xyz + 24576;          // (8,256,1024) = 2,097,152
  float* out_idx  = out_feat + 2097152;       // (8,1024)     = 8192

  ln_np2<<<64, 256, 0, stream>>>(features, ln_gamma, ln_beta, fbuf);
  gemm_f32<true, false><<<dim3(4, 256), 256, 0, stream>>>(fbuf, Wd1, bd1, nullptr, hbuf);
  wchain<<<64, 256, 0, stream>>>(hbuf, Wd2, bd2, wv);
  topk_kernel<<<8, 1024, 0, stream>>>(wv, xyzs, idx, out_xyz, out_idx);
  gemm_f32<true, true><<<dim3(4, 128), 256, 0, stream>>>(fbuf, Wu1, bu1, idx, hu);
  gemm_f32<false, false><<<dim3(4, 128), 256, 0, stream>>>(hu, Wu2, bu2, nullptr, nf);
  transpose_kernel<<<dim3(256, 8), 256, 0, stream>>>(nf, out_feat);
}

// Round 5
// 213.520 us; speedup vs baseline: 1.1280x; 1.1280x over previous
//
#include <hip/hip_runtime.h>

#define B_DIM 8
#define N_DIM 2048
#define C_DIM 256
#define K_SEL 1024

// ---------------- LayerNorm, numpy-bit-exact, LDS-staged ----------------
// Block = 64 rows (one b), 64 threads, tile[256][64] f32 = exactly 64 KB LDS.
// Swizzle: element (c,n) stored at c*64 + (n ^ (c&31)) -> conflict-free for
// fixed-c/lane-n reads AND fixed-n/lane-c reads.
// mu: single sequential ascending-c chain (numpy strided-axis outer reduction).
// var: numpy pairwise (2 halves x 8 accumulators) on contiguous (x-mu)^2.
__global__ __launch_bounds__(64) void ln_lds(const float* __restrict__ feat,
    const float* __restrict__ gamma, const float* __restrict__ beta,
    float* __restrict__ fbuf) {
  __shared__ float tile[256 * 64];   // 64 KB exactly
  const int t = threadIdx.x;
  const int m0 = blockIdx.x << 6;
  const int b = m0 >> 11, n0 = m0 & 2047;

  // --- load: 64 passes x (4 c-rows x 16 float4) ---
  const int cg = t >> 4, nl4 = (t & 15) << 2;
  for (int pass = 0; pass < 64; ++pass) {
    const int c = (pass << 2) + cg;
    const float4 v = *(const float4*)(feat + (((long)((b << 8) + c)) << 11) + n0 + nl4);
    const int sw = c & 31;
    float* row = tile + (c << 6);
    row[(nl4 + 0) ^ sw] = v.x; row[(nl4 + 1) ^ sw] = v.y;
    row[(nl4 + 2) ^ sw] = v.z; row[(nl4 + 3) ^ sw] = v.w;
  }
  __syncthreads();

  // --- mean: sequential ascending single chain (row n = t) ---
  float acc = tile[t];                       // c=0: addr 0 + (t^0)
  for (int c = 1; c < 256; ++c) acc = __fadd_rn(acc, tile[(c << 6) + (t ^ (c & 31))]);
  const float mu = __fdiv_rn(acc, 256.0f);

  // --- var: pairwise 2 halves x 8 accumulators ---
  float pw[2];
#pragma unroll
  for (int blk = 0; blk < 2; ++blk) {
    const int c0 = blk << 7;
    float r8[8];
#pragma unroll
    for (int j = 0; j < 8; ++j) {
      float d = __fsub_rn(tile[((c0 + j) << 6) + (t ^ ((c0 + j) & 31))], mu);
      r8[j] = __fmul_rn(d, d);
    }
    for (int i = 8; i < 128; i += 8) {
#pragma unroll
      for (int j = 0; j < 8; ++j) {
        const int c = c0 + i + j;
        float d = __fsub_rn(tile[(c << 6) + (t ^ (c & 31))], mu);
        r8[j] = __fadd_rn(r8[j], __fmul_rn(d, d));
      }
    }
    pw[blk] = __fadd_rn(__fadd_rn(__fadd_rn(r8[0], r8[1]), __fadd_rn(r8[2], r8[3])),
                        __fadd_rn(__fadd_rn(r8[4], r8[5]), __fadd_rn(r8[6], r8[7])));
  }
  const float var = __fdiv_rn(__fadd_rn(pw[0], pw[1]), 256.0f);
  const float rs = __fdiv_rn(1.0f, __fsqrt_rn(__fadd_rn(var, 1e-6f)));

  // --- normalize + coalesced write: lane = c-index now ---
  float ga[4], be[4];
#pragma unroll
  for (int q = 0; q < 4; ++q) { ga[q] = gamma[(q << 6) + t]; be[q] = beta[(q << 6) + t]; }
  for (int r = 0; r < 64; ++r) {
    const float mu_r = __shfl(mu, r, 64);
    const float rs_r = __shfl(rs, r, 64);
    float* orow = fbuf + (((long)(m0 + r)) << 8);
#pragma unroll
    for (int q = 0; q < 4; ++q) {
      const int c = (q << 6) + t;
      const float x = tile[(c << 6) + (r ^ (c & 31))];
      const float v = __fadd_rn(__fmul_rn(__fmul_rn(__fsub_rn(x, mu_r), rs_r), ga[q]), be[q]);
      orow[c] = v;
    }
  }
}

// ---------------- fused: h = relu(f@Wd1+bd1); w-chain -> key (bit-exact) ----------------
// Block = 64 rows x 256 cols, 256 threads, 8x8 acc (cols split 4+4 for bank spread).
// H staged in swizzled LDS aliased over As/Bs; wave 0 runs the ascending-c chain.
__global__ void __launch_bounds__(256) wgemm_w(
    const float* __restrict__ A, const float* __restrict__ Wd1,
    const float* __restrict__ bd1, const float* __restrict__ Wd2,
    const float* __restrict__ bd2, float* __restrict__ wkey) {
  __shared__ __align__(16) char smem[65536];
  float (*As)[68] = (float (*)[68])smem;               // 16x68x4 = 4352 B
  float (*Bs)[260] = (float (*)[260])(smem + 17408);   // 16x260x4 = 16640 B
  float* H = (float*)smem;                              // 64x256 swizzled (aliased)

  const int t = threadIdx.x;
  const int m0 = blockIdx.x << 6;
  const int rowT = t >> 5, colT = t & 31;
  const int ar = t >> 2, ak = (t & 3) << 2;
  const int bk = t >> 4, bc0 = (t & 15) << 4;
  const long arow = ((long)(m0 + ar)) << 8;
  float acc[8][8] = {};

  for (int k0 = 0; k0 < 256; k0 += 16) {
    const float4 av = *(const float4*)(A + arow + k0 + ak);
    As[ak + 0][ar] = av.x; As[ak + 1][ar] = av.y;
    As[ak + 2][ar] = av.z; As[ak + 3][ar] = av.w;
    const float* brow = Wd1 + (((k0 + bk) << 8) + bc0);
#pragma unroll
    for (int u = 0; u < 4; ++u)
      *(float4*)&Bs[bk][bc0 + (u << 2)] = *(const float4*)(brow + (u << 2));
    __syncthreads();
#pragma unroll
    for (int kk = 0; kk < 16; ++kk) {   // k ascending: single FMA chain per (m,c)
      const float4 a0 = *(const float4*)&As[kk][rowT << 3];
      const float4 a1 = *(const float4*)&As[kk][(rowT << 3) + 4];
      const float4 b0 = *(const float4*)&Bs[kk][colT << 2];
      const float4 b1 = *(const float4*)&Bs[kk][128 + (colT << 2)];
      const float aa[8] = {a0.x, a0.y, a0.z, a0.w, a1.x, a1.y, a1.z, a1.w};
      const float bb[8] = {b0.x, b0.y, b0.z, b0.w, b1.x, b1.y, b1.z, b1.w};
#pragma unroll
      for (int i = 0; i < 8; ++i)
#pragma unroll
        for (int j = 0; j < 8; ++j)
          acc[i][j] = __fmaf_rn(aa[i], bb[j], acc[i][j]);
    }
    __syncthreads();
  }

  // epilogue: bias + relu -> H (swizzled: addr m*256 + (c ^ (m&31)))
  const float4 bda = *(const float4*)(bd1 + (colT << 2));
  const float4 bdb = *(const float4*)(bd1 + 128 + (colT << 2));
  const float ba[8] = {bda.x, bda.y, bda.z, bda.w, bdb.x, bdb.y, bdb.z, bdb.w};
#pragma unroll
  for (int i = 0; i < 8; ++i) {
    const int m = (rowT << 3) + i;
    float* hrow = H + (m << 8);
    const int sw = m & 31;
#pragma unroll
    for (int j = 0; j < 8; ++j) {
      const int c = (j < 4) ? ((colT << 2) + j) : (128 + (colT << 2) + j - 4);
      hrow[c ^ sw] = fmaxf(__fadd_rn(acc[i][j], ba[j]), 0.0f);
    }
  }
  __syncthreads();

  // w-chain: ascending-c single FMA chain; key = (w+bd2)/0.1f
  if (t < 64) {
    const float* hrow = H + (t << 8);
    const int sw = t & 31;
    float wa = 0.0f;
    for (int c = 0; c < 256; ++c) wa = __fmaf_rn(hrow[c ^ sw], Wd2[c], wa);
    const float w = __fadd_rn(wa, bd2[0]);
    wkey[m0 + t] = __fdiv_rn(w, 0.1f);
  }
}

// ---------------- per-batch top-K: u64-packed bitonic (key desc, tie: lower idx) ----------------
__global__ void __launch_bounds__(1024) topk_kernel(
    const float* __restrict__ wv, const float* __restrict__ xyzs,
    int* __restrict__ idx_out, float* __restrict__ out_xyz,
    float* __restrict__ out_idx) {
  __shared__ unsigned long long vals[2048];
  const int b = blockIdx.x, t = threadIdx.x;
#pragma unroll
  for (int h = 0; h < 2; ++h) {
    const int i = (h << 10) + t;
    const unsigned int u = __float_as_uint(wv[(b << 11) + i]);
    const unsigned int up = ((int)u < 0) ? ~u : (u | 0x80000000u);
    vals[i] = (((unsigned long long)(~up)) << 32) | (unsigned int)i;  // ascending sort
  }
  __syncthreads();
  for (int k = 2; k <= 2048; k <<= 1) {
    for (int j = k >> 1; j > 0; j >>= 1) {
      for (int half = 0; half < 2; ++half) {
        const int i = (half << 10) | t;
        const int ixj = i ^ j;
        if (ixj > i) {
          const unsigned long long vi = vals[i], vj = vals[ixj];
          const bool up = ((i & k) == 0);
          if ((vi > vj) == up) { vals[i] = vj; vals[ixj] = vi; }
        }
      }
      __syncthreads();
    }
  }
  const int sel = (int)(vals[t] & 0xffffffffu);   // rank t == selection step t
  idx_out[(b << 10) + t] = sel;
  out_idx[(b << 10) + t] = (float)sel;
  const long o = ((long)((b << 10) + t)) * 3;
  const long s3 = ((long)((b << 11) + sel)) * 3;
  out_xyz[o] = xyzs[s3]; out_xyz[o + 1] = xyzs[s3 + 1]; out_xyz[o + 2] = xyzs[s3 + 2];
}

// ---------------- f32 64x64-tile GEMM (up-branch; ascending-k chain) ----------------
template <bool RELU, bool GATHER>
__global__ void __launch_bounds__(256) gemm_f32(
    const float* __restrict__ Ap, const float* __restrict__ Bw,
    const float* __restrict__ bias, const int* __restrict__ rowmap,
    float* __restrict__ Cout) {
  __shared__ __align__(16) float As[16][68];
  __shared__ __align__(16) float Bs[16][68];
  const int t = threadIdx.x;
  const int m0 = blockIdx.y << 6, c0 = blockIdx.x << 6;
  const int tx = t & 15, ty = t >> 4;
  const int ar = t >> 2, ak = (t & 3) << 2;
  long arow;
  if (GATHER) {
    int m = m0 + ar;
    arow = ((long)(((m >> 10) << 11) + rowmap[m])) << 8;
  } else {
    arow = ((long)(m0 + ar)) << 8;
  }
  const int bk = t >> 4, bc = (t & 15) << 2;
  float acc[4][4] = {};
  for (int k0 = 0; k0 < 256; k0 += 16) {
    const float4 av = *(const float4*)(Ap + arow + k0 + ak);
    const float4 bv = *(const float4*)(Bw + (((k0 + bk) << 8) + c0 + bc));
    As[ak + 0][ar] = av.x; As[ak + 1][ar] = av.y;
    As[ak + 2][ar] = av.z; As[ak + 3][ar] = av.w;
    *(float4*)&Bs[bk][bc] = bv;
    __syncthreads();
#pragma unroll
    for (int kk = 0; kk < 16; ++kk) {
      const float4 a = *(const float4*)&As[kk][ty << 2];
      const float4 b = *(const float4*)&Bs[kk][tx << 2];
      acc[0][0]=__fmaf_rn(a.x,b.x,acc[0][0]); acc[0][1]=__fmaf_rn(a.x,b.y,acc[0][1]);
      acc[0][2]=__fmaf_rn(a.x,b.z,acc[0][2]); acc[0][3]=__fmaf_rn(a.x,b.w,acc[0][3]);
      acc[1][0]=__fmaf_rn(a.y,b.x,acc[1][0]); acc[1][1]=__fmaf_rn(a.y,b.y,acc[1][1]);
      acc[1][2]=__fmaf_rn(a.y,b.z,acc[1][2]); acc[1][3]=__fmaf_rn(a.y,b.w,acc[1][3]);
      acc[2][0]=__fmaf_rn(a.z,b.x,acc[2][0]); acc[2][1]=__fmaf_rn(a.z,b.y,acc[2][1]);
      acc[2][2]=__fmaf_rn(a.z,b.z,acc[2][2]); acc[2][3]=__fmaf_rn(a.z,b.w,acc[2][3]);
      acc[3][0]=__fmaf_rn(a.w,b.x,acc[3][0]); acc[3][1]=__fmaf_rn(a.w,b.y,acc[3][1]);
      acc[3][2]=__fmaf_rn(a.w,b.z,acc[3][2]); acc[3][3]=__fmaf_rn(a.w,b.w,acc[3][3]);
    }
    __syncthreads();
  }
  const int cc = c0 + (tx << 2);
#pragma unroll
  for (int r = 0; r < 4; ++r) {
    float o0 = __fadd_rn(acc[r][0], bias[cc + 0]);
    float o1 = __fadd_rn(acc[r][1], bias[cc + 1]);
    float o2 = __fadd_rn(acc[r][2], bias[cc + 2]);
    float o3 = __fadd_rn(acc[r][3], bias[cc + 3]);
    if (RELU) { o0 = fmaxf(o0,0.0f); o1 = fmaxf(o1,0.0f); o2 = fmaxf(o2,0.0f); o3 = fmaxf(o3,0.0f); }
    float4 o; o.x=o0; o.y=o1; o.z=o2; o.w=o3;
    *(float4*)(Cout + (((long)(m0 + (ty << 2) + r)) << 8) + cc) = o;
  }
}

// ---------------- feats transpose: nf (B*K, C) -> out (B, C, K) ----------------
__global__ void __launch_bounds__(256) transpose_kernel(
    const float* __restrict__ nf, float* __restrict__ outf) {
  __shared__ float tile[32][33];
  const int kt = blockIdx.x, ct = blockIdx.y, t = threadIdx.x;
  const int k0 = kt << 5, c0 = ct << 5;
  const int col = t & 31, row8 = t >> 5;
#pragma unroll
  for (int p = 0; p < 4; ++p) {
    int kr = (p << 3) + row8;
    tile[kr][col] = nf[((long)(k0 + kr) << 8) + c0 + col];
  }
  __syncthreads();
  const int bb = k0 >> 10;
  const int kk = k0 & 1023;
#pragma unroll
  for (int p = 0; p < 4; ++p) {
    int cr = (p << 3) + row8;
    outf[((long)((bb << 8) + c0 + cr) << 10) + kk + col] = tile[col][cr];
  }
}

extern "C" void kernel_launch(void* const* d_in, const int* in_sizes, int n_in,
                              void* d_out, int out_size, void* d_ws, size_t ws_size,
                              hipStream_t stream) {
  const float* xyzs     = (const float*)d_in[0];
  const float* features = (const float*)d_in[1];
  const float* ln_gamma = (const float*)d_in[2];
  const float* ln_beta  = (const float*)d_in[3];
  const float* Wu1      = (const float*)d_in[4];
  const float* bu1      = (const float*)d_in[5];
  const float* Wu2      = (const float*)d_in[6];
  const float* bu2      = (const float*)d_in[7];
  const float* Wd1      = (const float*)d_in[8];
  const float* bd1      = (const float*)d_in[9];
  const float* Wd2      = (const float*)d_in[10];
  const float* bd2      = (const float*)d_in[11];

  char* ws = (char*)d_ws;
  float* fbuf = (float*)ws;                   // 16384*256 f32 = 16 MB
  float* hu   = (float*)(ws + 33554432);      //  8192*256 f32
  float* nf   = (float*)(ws + 41943040);      //  8192*256 f32
  float* wv   = (float*)(ws + 50331648);      // 16384 f32
  int*   idx  = (int*)(ws + 50397184);        //  8192 i32

  float* out_xyz  = (float*)d_out;            // (8,1024,3)
  float* out_feat = out_xyz + 24576;          // (8,256,1024)
  float* out_idx  = out_feat + 2097152;       // (8,1024)

  ln_lds<<<256, 64, 0, stream>>>(features, ln_gamma, ln_beta, fbuf);
  wgemm_w<<<256, 256, 0, stream>>>(fbuf, Wd1, bd1, Wd2, bd2, wv);
  topk_kernel<<<8, 1024, 0, stream>>>(wv, xyzs, idx, out_xyz, out_idx);
  gemm_f32<true, true><<<dim3(4, 128), 256, 0, stream>>>(fbuf, Wu1, bu1, idx, hu);
  gemm_f32<false, false><<<dim3(4, 128), 256, 0, stream>>>(hu, Wu2, bu2, nullptr, nf);
  transpose_kernel<<<dim3(256, 8), 256, 0, stream>>>(nf, out_feat);
}

// Round 6
// 196.734 us; speedup vs baseline: 1.2242x; 1.0853x over previous
//
#include <hip/hip_runtime.h>

#define B_DIM 8
#define N_DIM 2048
#define C_DIM 256
#define K_SEL 1024

typedef __attribute__((ext_vector_type(8))) short short8;
typedef __attribute__((ext_vector_type(4))) float f32x4;

__device__ __forceinline__ unsigned int bf16rne(float x) {
  unsigned int u = __float_as_uint(x);
  return (u + 0x7fffu + ((u >> 16) & 1u)) >> 16;
}

// ---------------- LayerNorm, numpy-bit-exact, LDS-staged (unchanged, verified) ----------------
__global__ __launch_bounds__(64) void ln_lds(const float* __restrict__ feat,
    const float* __restrict__ gamma, const float* __restrict__ beta,
    float* __restrict__ fbuf) {
  __shared__ float tile[256 * 64];   // 64 KB exactly
  const int t = threadIdx.x;
  const int m0 = blockIdx.x << 6;
  const int b = m0 >> 11, n0 = m0 & 2047;

  const int cg = t >> 4, nl4 = (t & 15) << 2;
  for (int pass = 0; pass < 64; ++pass) {
    const int c = (pass << 2) + cg;
    const float4 v = *(const float4*)(feat + (((long)((b << 8) + c)) << 11) + n0 + nl4);
    const int sw = c & 31;
    float* row = tile + (c << 6);
    row[(nl4 + 0) ^ sw] = v.x; row[(nl4 + 1) ^ sw] = v.y;
    row[(nl4 + 2) ^ sw] = v.z; row[(nl4 + 3) ^ sw] = v.w;
  }
  __syncthreads();

  // mean: sequential ascending single chain (numpy strided-axis outer reduction)
  float acc = tile[t];
  for (int c = 1; c < 256; ++c) acc = __fadd_rn(acc, tile[(c << 6) + (t ^ (c & 31))]);
  const float mu = __fdiv_rn(acc, 256.0f);

  // var: numpy pairwise (2 halves x 8 accumulators) on contiguous (x-mu)^2
  float pw[2];
#pragma unroll
  for (int blk = 0; blk < 2; ++blk) {
    const int c0 = blk << 7;
    float r8[8];
#pragma unroll
    for (int j = 0; j < 8; ++j) {
      float d = __fsub_rn(tile[((c0 + j) << 6) + (t ^ ((c0 + j) & 31))], mu);
      r8[j] = __fmul_rn(d, d);
    }
    for (int i = 8; i < 128; i += 8) {
#pragma unroll
      for (int j = 0; j < 8; ++j) {
        const int c = c0 + i + j;
        float d = __fsub_rn(tile[(c << 6) + (t ^ (c & 31))], mu);
        r8[j] = __fadd_rn(r8[j], __fmul_rn(d, d));
      }
    }
    pw[blk] = __fadd_rn(__fadd_rn(__fadd_rn(r8[0], r8[1]), __fadd_rn(r8[2], r8[3])),
                        __fadd_rn(__fadd_rn(r8[4], r8[5]), __fadd_rn(r8[6], r8[7])));
  }
  const float var = __fdiv_rn(__fadd_rn(pw[0], pw[1]), 256.0f);
  const float rs = __fdiv_rn(1.0f, __fsqrt_rn(__fadd_rn(var, 1e-6f)));

  float ga[4], be[4];
#pragma unroll
  for (int q = 0; q < 4; ++q) { ga[q] = gamma[(q << 6) + t]; be[q] = beta[(q << 6) + t]; }
  for (int r = 0; r < 64; ++r) {
    const float mu_r = __shfl(mu, r, 64);
    const float rs_r = __shfl(rs, r, 64);
    float* orow = fbuf + (((long)(m0 + r)) << 8);
#pragma unroll
    for (int q = 0; q < 4; ++q) {
      const int c = (q << 6) + t;
      const float x = tile[(c << 6) + (r ^ (c & 31))];
      orow[c] = __fadd_rn(__fmul_rn(__fmul_rn(__fsub_rn(x, mu_r), rs_r), ga[q]), be[q]);
    }
  }
}

// ---------------- fused down-GEMM + w-chain, 512 threads (bit-exact chains) ----------------
// 64 rows x 256 cols, 8x4 acc. H in [c][m] layout, swizzle H[c*64 + (m ^ ((c>>2)&31))]:
// epilogue writes (lanes span colT) and w-chain reads (lanes span m) both hit 32 banks.
__global__ void __launch_bounds__(512) wgemm_w(
    const float* __restrict__ A, const float* __restrict__ Wd1,
    const float* __restrict__ bd1, const float* __restrict__ Wd2,
    const float* __restrict__ bd2, float* __restrict__ wkey) {
  __shared__ __align__(16) char smem[65536];
  float (*As)[68] = (float (*)[68])smem;               // 16x68x4 = 4352 B
  float (*Bs)[260] = (float (*)[260])(smem + 4352);    // 16x260x4 = 16640 B
  float* H = (float*)smem;                              // 256x64 f32 = 64 KB (aliased)

  const int t = threadIdx.x;
  const int m0 = blockIdx.x << 6;
  const int rowT = t >> 6, colT = t & 63;
  const int ar = t >> 2, ak = (t & 3) << 2;             // A loaders: t<256
  const int bk = t >> 5, bc = (t & 31) << 3;            // B loaders: all 512
  const long arow = ((long)(m0 + ar)) << 8;
  float acc[8][4] = {};

  for (int k0 = 0; k0 < 256; k0 += 16) {
    if (t < 256) {
      const float4 av = *(const float4*)(A + arow + k0 + ak);
      As[ak + 0][ar] = av.x; As[ak + 1][ar] = av.y;
      As[ak + 2][ar] = av.z; As[ak + 3][ar] = av.w;
    }
    const float* brow = Wd1 + (((k0 + bk) << 8) + bc);
    *(float4*)&Bs[bk][bc] = *(const float4*)brow;
    *(float4*)&Bs[bk][bc + 4] = *(const float4*)(brow + 4);
    __syncthreads();
#pragma unroll
    for (int kk = 0; kk < 16; ++kk) {   // k ascending: single FMA chain per (m,c)
      const float4 a0 = *(const float4*)&As[kk][rowT << 3];
      const float4 a1 = *(const float4*)&As[kk][(rowT << 3) + 4];
      const float4 b = *(const float4*)&Bs[kk][colT << 2];
      const float aa[8] = {a0.x, a0.y, a0.z, a0.w, a1.x, a1.y, a1.z, a1.w};
      const float bbv[4] = {b.x, b.y, b.z, b.w};
#pragma unroll
      for (int i = 0; i < 8; ++i)
#pragma unroll
        for (int j = 0; j < 4; ++j)
          acc[i][j] = __fmaf_rn(aa[i], bbv[j], acc[i][j]);
    }
    __syncthreads();
  }

  // epilogue: bias + relu -> H[c][m] swizzled
  const float4 bd = *(const float4*)(bd1 + (colT << 2));
  const float ba[4] = {bd.x, bd.y, bd.z, bd.w};
#pragma unroll
  for (int i = 0; i < 8; ++i) {
    const int m = (rowT << 3) + i;
#pragma unroll
    for (int j = 0; j < 4; ++j) {
      const int c = (colT << 2) + j;
      H[(c << 6) + (m ^ ((c >> 2) & 31))] = fmaxf(__fadd_rn(acc[i][j], ba[j]), 0.0f);
    }
  }
  __syncthreads();

  // w-chain: ascending-c single FMA chain; key = (w+bd2)/0.1f
  if (t < 64) {
    float wa = 0.0f;
    for (int c = 0; c < 256; ++c)
      wa = __fmaf_rn(H[(c << 6) + (t ^ ((c >> 2) & 31))], Wd2[c], wa);
    const float w = __fadd_rn(wa, bd2[0]);
    wkey[m0 + t] = __fdiv_rn(w, 0.1f);
  }
}

// ---------------- per-batch top-K: u64-packed bitonic (key desc, tie: lower idx) ----------------
__global__ void __launch_bounds__(1024) topk_kernel(
    const float* __restrict__ wv, const float* __restrict__ xyzs,
    int* __restrict__ idx_out, float* __restrict__ out_xyz,
    float* __restrict__ out_idx) {
  __shared__ unsigned long long vals[2048];
  const int b = blockIdx.x, t = threadIdx.x;
#pragma unroll
  for (int h = 0; h < 2; ++h) {
    const int i = (h << 10) + t;
    const unsigned int u = __float_as_uint(wv[(b << 11) + i]);
    const unsigned int up = ((int)u < 0) ? ~u : (u | 0x80000000u);
    vals[i] = (((unsigned long long)(~up)) << 32) | (unsigned int)i;
  }
  __syncthreads();
  for (int k = 2; k <= 2048; k <<= 1) {
    for (int j = k >> 1; j > 0; j >>= 1) {
      for (int half = 0; half < 2; ++half) {
        const int i = (half << 10) | t;
        const int ixj = i ^ j;
        if (ixj > i) {
          const unsigned long long vi = vals[i], vj = vals[ixj];
          const bool up = ((i & k) == 0);
          if ((vi > vj) == up) { vals[i] = vj; vals[ixj] = vi; }
        }
      }
      __syncthreads();
    }
  }
  const int sel = (int)(vals[t] & 0xffffffffu);
  idx_out[(b << 10) + t] = sel;
  out_idx[(b << 10) + t] = (float)sel;
  const long o = ((long)((b << 10) + t)) * 3;
  const long s3 = ((long)((b << 11) + sel)) * 3;
  out_xyz[o] = xyzs[s3]; out_xyz[o + 1] = xyzs[s3 + 1]; out_xyz[o + 2] = xyzs[s3 + 2];
}

// ---------------- weight prep: W (256x256 f32) -> P bf16 slabs [kc][n][32] ----------------
__global__ __launch_bounds__(256) void prep_w(const float* __restrict__ W,
    unsigned short* __restrict__ P) {
  const int kc = blockIdx.x, n = threadIdx.x;
  unsigned int packed[16];
#pragma unroll
  for (int i = 0; i < 16; ++i) {
    const float a = W[(((kc << 5) + 2 * i) << 8) + n];
    const float bq = W[(((kc << 5) + 2 * i + 1) << 8) + n];
    packed[i] = bf16rne(a) | (bf16rne(bq) << 16);
  }
  uint4* dst = (uint4*)(P + (((kc << 8) + n) << 5));
#pragma unroll
  for (int q = 0; q < 4; ++q)
    dst[q] = make_uint4(packed[4 * q], packed[4 * q + 1], packed[4 * q + 2], packed[4 * q + 3]);
}

// ---------------- fused up-branch: gather -> bf16 MFMA GEMM1(relu) -> GEMM2 -> transposed out ----------------
#define APITCH 264
#define BPITCH 40
__global__ void __launch_bounds__(256) up_mfma(
    const float* __restrict__ fbuf, const int* __restrict__ idxm,
    const unsigned short* __restrict__ Wu1P, const float* __restrict__ bu1,
    const unsigned short* __restrict__ Wu2P, const float* __restrict__ bu2,
    float* __restrict__ out_feat) {
  __shared__ __align__(16) char smem[64 * APITCH * 2 + 256 * BPITCH * 2 + 2048];
  unsigned short* As = (unsigned short*)smem;                       // 33792 B (later Hs)
  unsigned short* Bs = (unsigned short*)(smem + 64 * APITCH * 2);   // 20480 B (later T)
  float* bias1 = (float*)(smem + 64 * APITCH * 2 + 256 * BPITCH * 2);
  float* bias2 = bias1 + 256;
  float* T = (float*)(smem + 64 * APITCH * 2);                      // 64x66 f32 = 16896 B

  const int t = threadIdx.x;
  const int m0 = blockIdx.x << 6;
  const int quad = (t >> 4) & 3, ln = t & 15, w = t >> 6;

  bias1[t] = bu1[t];
  bias2[t] = bu2[t];

  // gather + cvt: As[r][c] bf16, r = t&63, cols (t>>6)*64..+63
  {
    const int r = t & 63, cseg = t >> 6;
    const int m = m0 + r;
    const long srow = (long)(((m >> 10) << 11) + idxm[m]) << 8;
    const float* src = fbuf + srow + (cseg << 6);
    unsigned short* dst = As + r * APITCH + (cseg << 6);
#pragma unroll
    for (int u = 0; u < 16; ++u) {
      const float4 v = *(const float4*)(src + (u << 2));
      const unsigned int lo = bf16rne(v.x) | (bf16rne(v.y) << 16);
      const unsigned int hi = bf16rne(v.z) | (bf16rne(v.w) << 16);
      *(uint2*)(dst + (u << 2)) = make_uint2(lo, hi);
    }
  }

  f32x4 acc[16];
#pragma unroll
  for (int i = 0; i < 16; ++i) acc[i] = (f32x4){0.f, 0.f, 0.f, 0.f};

  // ---- GEMM1: hu = gathered_f @ Wu1 ----
  for (int kc = 0; kc < 8; ++kc) {
    __syncthreads();
    const uint4* sb = (const uint4*)(Wu1P + (((kc << 8) + t) << 5));
    uint4* db = (uint4*)(Bs + t * BPITCH);
    db[0] = sb[0]; db[1] = sb[1]; db[2] = sb[2]; db[3] = sb[3];
    __syncthreads();
    const short8 a = *(const short8*)(As + ((w << 4) + ln) * APITCH + (kc << 5) + (quad << 3));
#pragma unroll
    for (int nt = 0; nt < 16; ++nt) {
      const short8 b = *(const short8*)(Bs + ((nt << 4) + ln) * BPITCH + (quad << 3));
      acc[nt] = __builtin_amdgcn_mfma_f32_16x16x32_bf16(a, b, acc[nt], 0, 0, 0);
    }
  }

  // ---- relu + bias -> Hs (alias As) ----
  __syncthreads();
  unsigned short* Hs = As;
#pragma unroll
  for (int nt = 0; nt < 16; ++nt) {
    const int c = (nt << 4) + ln;
    const float bb = bias1[c];
#pragma unroll
    for (int rr = 0; rr < 4; ++rr) {
      const float h = fmaxf(acc[nt][rr] + bb, 0.0f);
      Hs[((w << 4) + (quad << 2) + rr) * APITCH + c] = (unsigned short)bf16rne(h);
    }
  }
#pragma unroll
  for (int i = 0; i < 16; ++i) acc[i] = (f32x4){0.f, 0.f, 0.f, 0.f};

  // ---- GEMM2: nf = hu @ Wu2 ----
  for (int kc = 0; kc < 8; ++kc) {
    __syncthreads();
    const uint4* sb = (const uint4*)(Wu2P + (((kc << 8) + t) << 5));
    uint4* db = (uint4*)(Bs + t * BPITCH);
    db[0] = sb[0]; db[1] = sb[1]; db[2] = sb[2]; db[3] = sb[3];
    __syncthreads();
    const short8 a = *(const short8*)(Hs + ((w << 4) + ln) * APITCH + (kc << 5) + (quad << 3));
#pragma unroll
    for (int nt = 0; nt < 16; ++nt) {
      const short8 b = *(const short8*)(Bs + ((nt << 4) + ln) * BPITCH + (quad << 3));
      acc[nt] = __builtin_amdgcn_mfma_f32_16x16x32_bf16(a, b, acc[nt], 0, 0, 0);
    }
  }

  // ---- epilogue: +bu2, transpose via LDS, write out_feat (B,C,K) coalesced ----
  const int bb = m0 >> 10, kbase = m0 & 1023;
  for (int ci = 0; ci < 4; ++ci) {
    __syncthreads();
#pragma unroll
    for (int q = 0; q < 4; ++q) {
      const int nt = (ci << 2) + q;
      const int cloc = (q << 4) + ln;
      const float b2 = bias2[(nt << 4) + ln];
#pragma unroll
      for (int rr = 0; rr < 4; ++rr)
        T[cloc * 66 + ((w << 4) + (quad << 2) + rr)] = acc[nt][rr] + b2;
    }
    __syncthreads();
#pragma unroll
    for (int p = 0; p < 16; ++p) {
      const int cl = (p << 2) + (t >> 6);
      const int m = t & 63;
      out_feat[((long)((bb << 8) + (ci << 6) + cl) << 10) + kbase + m] = T[cl * 66 + m];
    }
  }
}

extern "C" void kernel_launch(void* const* d_in, const int* in_sizes, int n_in,
                              void* d_out, int out_size, void* d_ws, size_t ws_size,
                              hipStream_t stream) {
  const float* xyzs     = (const float*)d_in[0];
  const float* features = (const float*)d_in[1];
  const float* ln_gamma = (const float*)d_in[2];
  const float* ln_beta  = (const float*)d_in[3];
  const float* Wu1      = (const float*)d_in[4];
  const float* bu1      = (const float*)d_in[5];
  const float* Wu2      = (const float*)d_in[6];
  const float* bu2      = (const float*)d_in[7];
  const float* Wd1      = (const float*)d_in[8];
  const float* bd1      = (const float*)d_in[9];
  const float* Wd2      = (const float*)d_in[10];
  const float* bd2      = (const float*)d_in[11];

  char* ws = (char*)d_ws;
  float* fbuf = (float*)ws;                              // 16 MB
  unsigned short* Wu1P = (unsigned short*)(ws + 33554432);  // 128 KB bf16 slabs
  unsigned short* Wu2P = (unsigned short*)(ws + 33685504);  // 128 KB
  float* wv   = (float*)(ws + 50331648);                 // 16384 f32
  int*   idx  = (int*)(ws + 50397184);                   // 8192 i32

  float* out_xyz  = (float*)d_out;            // (8,1024,3)
  float* out_feat = out_xyz + 24576;          // (8,256,1024)
  float* out_idx  = out_feat + 2097152;       // (8,1024)

  prep_w<<<8, 256, 0, stream>>>(Wu1, Wu1P);
  prep_w<<<8, 256, 0, stream>>>(Wu2, Wu2P);
  ln_lds<<<256, 64, 0, stream>>>(features, ln_gamma, ln_beta, fbuf);
  wgemm_w<<<256, 512, 0, stream>>>(fbuf, Wd1, bd1, Wd2, bd2, wv);
  topk_kernel<<<8, 1024, 0, stream>>>(wv, xyzs, idx, out_xyz, out_idx);
  up_mfma<<<128, 256, 0, stream>>>(fbuf, idx, Wu1P, bu1, Wu2P, bu2, out_feat);
}